// Round 1
// baseline (3795.713 us; speedup 1.0000x reference)
//
#include <hip/hip_runtime.h>
#include <math.h>

#define B_    64
#define T_    256
#define N_    61
#define FIN_  3
#define GH_   64
#define LH_   128
#define NC_   10
#define NG_   3904      /* N_*GH_ */
#define M_TOT 16384     /* B_*T_  */
#define CHUNK_M 4096

__device__ __forceinline__ float gelu_exact(float x) {
    return 0.5f * x * (1.0f + erff(x * 0.70710678118654752f));
}
__device__ __forceinline__ float sigmoidf_(float x) {
    return 1.0f / (1.0f + expf(-x));
}

// ---------------------------------------------------------------------------
// GCN: one block per (b,t). Everything staged in LDS (63.9 KB).
// h = gelu( A @ gelu( (A @ X) @ W1^T + b1 ) @ ... ) -> seq row (3904 f32)
// ---------------------------------------------------------------------------
__global__ __launch_bounds__(256) void gcn_kernel(
    const float* __restrict__ x, const float* __restrict__ adj,
    const float* __restrict__ W1, const float* __restrict__ b1,
    const float* __restrict__ W2, const float* __restrict__ b2,
    float* __restrict__ seqc, int m_base)
{
    __shared__ float adjs[N_ * N_];           // 3721
    __shared__ float xs [N_ * FIN_ + 1];      // 183
    __shared__ float axs[N_ * FIN_ + 1];
    __shared__ float h1s [N_ * GH_];          // 3904
    __shared__ float ah1s[N_ * GH_];
    __shared__ float w2s[GH_ * (GH_ + 1)];    // stride 65: kills bank conflicts
    __shared__ float w1s[GH_ * FIN_];
    __shared__ float b1s[GH_], b2s[GH_];

    const int tid = threadIdx.x;
    const int m   = m_base + blockIdx.x;

    for (int i = tid; i < N_ * N_;   i += 256) adjs[i] = adj[i];
    for (int i = tid; i < N_ * FIN_; i += 256) xs[i]   = x[(size_t)m * (N_ * FIN_) + i];
    for (int i = tid; i < GH_ * FIN_; i += 256) w1s[i] = W1[i];
    if (tid < GH_) { b1s[tid] = b1[tid]; b2s[tid] = b2[tid]; }
    for (int i = tid; i < GH_ * GH_; i += 256) {
        int c = i >> 6, f = i & 63;
        w2s[c * 65 + f] = W2[i];
    }
    __syncthreads();

    // AX (61x3)
    if (tid < N_ * FIN_) {
        int n = tid / 3, f = tid - n * 3;
        float acc = 0.f;
        for (int mm = 0; mm < N_; ++mm) acc += adjs[n * N_ + mm] * xs[mm * 3 + f];
        axs[tid] = acc;
    }
    __syncthreads();

    // H1 = gelu(AX @ W1^T + b1)   (61x64)
    for (int u = 0; u < 16; ++u) {
        int idx = tid + u * 256;
        if (idx < N_ * GH_) {
            int n = idx >> 6, c = idx & 63;
            float acc = b1s[c];
            acc += axs[n * 3 + 0] * w1s[c * 3 + 0];
            acc += axs[n * 3 + 1] * w1s[c * 3 + 1];
            acc += axs[n * 3 + 2] * w1s[c * 3 + 2];
            h1s[idx] = gelu_exact(acc);
        }
    }
    __syncthreads();

    // AH1 = A @ H1
    for (int u = 0; u < 16; ++u) {
        int idx = tid + u * 256;
        if (idx < N_ * GH_) {
            int n = idx >> 6, c = idx & 63;
            float acc = 0.f;
            for (int mm = 0; mm < N_; ++mm) acc += adjs[n * N_ + mm] * h1s[mm * GH_ + c];
            ah1s[idx] = acc;
        }
    }
    __syncthreads();

    // H2 = gelu(AH1 @ W2^T + b2) -> seq
    for (int u = 0; u < 16; ++u) {
        int idx = tid + u * 256;
        if (idx < N_ * GH_) {
            int n = idx >> 6, c = idx & 63;
            float acc = b2s[c];
            #pragma unroll
            for (int f = 0; f < GH_; ++f) acc += ah1s[n * GH_ + f] * w2s[c * 65 + f];
            seqc[(size_t)blockIdx.x * NG_ + idx] = gelu_exact(acc);
        }
    }
}

// ---------------------------------------------------------------------------
// fp32 GEMM: C = A(McxK) @ W(1024xK)^T + bias_a + bias_b
// 128x128 tile, 256 threads, 8x8 micro-tile. Output scattered to [d][Mtot][512].
// ---------------------------------------------------------------------------
__global__ __launch_bounds__(256) void gemm_bias_kernel(
    const float* __restrict__ A, const float* __restrict__ W,
    const float* __restrict__ bias_a, const float* __restrict__ bias_b,
    float* __restrict__ Cout, int K, int m_base, int Mtot)
{
    __shared__ float As[16][132];
    __shared__ float Bs[16][132];
    const int tid = threadIdx.x;
    const int tx = tid & 15, ty = tid >> 4;
    const int m0 = blockIdx.x * 128;
    const int n0 = blockIdx.y * 128;
    const int lr = tid >> 1;
    const int lk = (tid & 1) * 8;

    float acc[8][8];
    #pragma unroll
    for (int i = 0; i < 8; ++i)
        #pragma unroll
        for (int j = 0; j < 8; ++j) acc[i][j] = 0.f;

    const float* aptr = A + (size_t)(m0 + lr) * K + lk;
    const float* bptr = W + (size_t)(n0 + lr) * K + lk;

    for (int k0 = 0; k0 < K; k0 += 16) {
        float4 a0 = *reinterpret_cast<const float4*>(aptr);
        float4 a1 = *reinterpret_cast<const float4*>(aptr + 4);
        float4 b0 = *reinterpret_cast<const float4*>(bptr);
        float4 b1 = *reinterpret_cast<const float4*>(bptr + 4);
        As[lk + 0][lr] = a0.x; As[lk + 1][lr] = a0.y; As[lk + 2][lr] = a0.z; As[lk + 3][lr] = a0.w;
        As[lk + 4][lr] = a1.x; As[lk + 5][lr] = a1.y; As[lk + 6][lr] = a1.z; As[lk + 7][lr] = a1.w;
        Bs[lk + 0][lr] = b0.x; Bs[lk + 1][lr] = b0.y; Bs[lk + 2][lr] = b0.z; Bs[lk + 3][lr] = b0.w;
        Bs[lk + 4][lr] = b1.x; Bs[lk + 5][lr] = b1.y; Bs[lk + 6][lr] = b1.z; Bs[lk + 7][lr] = b1.w;
        __syncthreads();
        #pragma unroll
        for (int kk = 0; kk < 16; ++kk) {
            float4 av0 = *reinterpret_cast<const float4*>(&As[kk][ty * 8]);
            float4 av1 = *reinterpret_cast<const float4*>(&As[kk][ty * 8 + 4]);
            float4 bv0 = *reinterpret_cast<const float4*>(&Bs[kk][tx * 4]);
            float4 bv1 = *reinterpret_cast<const float4*>(&Bs[kk][64 + tx * 4]);
            float a[8]  = {av0.x, av0.y, av0.z, av0.w, av1.x, av1.y, av1.z, av1.w};
            float bb[8] = {bv0.x, bv0.y, bv0.z, bv0.w, bv1.x, bv1.y, bv1.z, bv1.w};
            #pragma unroll
            for (int i = 0; i < 8; ++i)
                #pragma unroll
                for (int j = 0; j < 8; ++j) acc[i][j] += a[i] * bb[j];
        }
        __syncthreads();
        aptr += 16; bptr += 16;
    }

    #pragma unroll
    for (int i = 0; i < 8; ++i) {
        int m = m_base + m0 + ty * 8 + i;
        #pragma unroll
        for (int j = 0; j < 8; ++j) {
            int n = n0 + ((j < 4) ? (tx * 4 + j) : (64 + tx * 4 + j - 4));
            float v = acc[i][j] + bias_a[n] + bias_b[n];
            int d = n >> 9, g = n & 511;
            Cout[((size_t)d * Mtot + m) * 512 + g] = v;
        }
    }
}

// ---------------------------------------------------------------------------
// BiLSTM recurrence: one block per (dir,batch). 1024 threads.
// thread = (gate g in [0,512), k-half kh in {0,1}); 64 Whh weights in registers.
// ---------------------------------------------------------------------------
__global__ __launch_bounds__(1024) void lstm_kernel(
    const float* __restrict__ pre,   // [d][b][t][512]
    const float* __restrict__ Whh,   // [2][512][128]
    float* __restrict__ hout)        // [b][t][256]  (dir d -> cols d*128..)
{
    const int d   = blockIdx.x >> 6;
    const int b   = blockIdx.x & 63;
    const int tid = threadIdx.x;
    const int g   = tid & 511;
    const int kh  = tid >> 9;

    float w[64];
    const float* wsrc = Whh + ((size_t)d * 512 + g) * 128 + kh * 64;
    #pragma unroll
    for (int k = 0; k < 64; ++k) w[k] = wsrc[k];

    __shared__ __align__(16) float h_lds[128];
    __shared__ float part[1024];
    __shared__ float gates[512];

    if (tid < 128) h_lds[tid] = 0.f;
    float c = 0.f;
    __syncthreads();

    const float* prebase = pre + ((size_t)(d * B_ + b)) * T_ * 512;

    for (int s = 0; s < T_; ++s) {
        int t = d ? (T_ - 1 - s) : s;
        float p = (tid < 512) ? prebase[(size_t)t * 512 + g] : 0.f;

        float acc0 = 0.f, acc1 = 0.f;
        #pragma unroll
        for (int k4 = 0; k4 < 16; ++k4) {
            float4 hv = *reinterpret_cast<const float4*>(&h_lds[kh * 64 + k4 * 4]);
            acc0 += w[k4 * 4 + 0] * hv.x; acc1 += w[k4 * 4 + 1] * hv.y;
            acc0 += w[k4 * 4 + 2] * hv.z; acc1 += w[k4 * 4 + 3] * hv.w;
        }
        part[tid] = acc0 + acc1;
        __syncthreads();
        if (tid < 512) gates[g] = p + part[g] + part[g + 512];
        __syncthreads();
        if (tid < 128) {
            float gi = gates[tid], gf = gates[tid + 128];
            float gc = gates[tid + 256], go = gates[tid + 384];
            c = sigmoidf_(gf) * c + sigmoidf_(gi) * tanhf(gc);
            float h = sigmoidf_(go) * tanhf(c);
            h_lds[tid] = h;
            hout[((size_t)b * T_ + t) * 256 + d * 128 + tid] = h;
        }
        __syncthreads();
    }
}

// ---------------------------------------------------------------------------
// attention scores: block per b; thread=(j in [0,64), k-quarter); Wa1 in regs.
// ---------------------------------------------------------------------------
__global__ __launch_bounds__(256) void attn_scores_kernel(
    const float* __restrict__ l1, const float* __restrict__ Wa1,
    const float* __restrict__ ba1, const float* __restrict__ Wa2,
    const float* __restrict__ ba2, float* __restrict__ scores)
{
    const int b   = blockIdx.x;
    const int tid = threadIdx.x;
    const int j   = tid & 63, kq = tid >> 6;

    float w[64];
    const float* wsrc = Wa1 + j * 256 + kq * 64;
    #pragma unroll
    for (int k = 0; k < 64; ++k) w[k] = wsrc[k];

    __shared__ __align__(16) float row[256];
    __shared__ float part[256];
    const float* lb  = l1 + (size_t)b * T_ * 256;
    float wa2 = (tid < 64) ? Wa2[tid] : 0.f;
    float bj  = (tid < 64) ? ba1[tid] : 0.f;
    float bb2 = ba2[0];

    for (int t = 0; t < T_; ++t) {
        __syncthreads();
        row[tid] = lb[(size_t)t * 256 + tid];
        __syncthreads();
        float acc = 0.f;
        #pragma unroll
        for (int k4 = 0; k4 < 16; ++k4) {
            float4 hv = *reinterpret_cast<const float4*>(&row[kq * 64 + k4 * 4]);
            acc += w[k4 * 4 + 0] * hv.x + w[k4 * 4 + 1] * hv.y
                 + w[k4 * 4 + 2] * hv.z + w[k4 * 4 + 3] * hv.w;
        }
        part[tid] = acc;
        __syncthreads();
        if (tid < 64) {
            float dj = part[tid] + part[tid + 64] + part[tid + 128] + part[tid + 192];
            float sv = tanhf(dj + bj) * wa2;
            #pragma unroll
            for (int off = 32; off > 0; off >>= 1) sv += __shfl_xor(sv, off);
            if (tid == 0) scores[b * T_ + t] = sv + bb2;
        }
    }
}

// ---------------------------------------------------------------------------
// softmax over t + context + classifier head: block per b.
// ---------------------------------------------------------------------------
__global__ __launch_bounds__(256) void attn_head_kernel(
    const float* __restrict__ l1, const float* __restrict__ scores,
    const float* __restrict__ Wc1, const float* __restrict__ bc1,
    const float* __restrict__ Wc2, const float* __restrict__ bc2,
    float* __restrict__ out)
{
    const int b   = blockIdx.x;
    const int tid = threadIdx.x;
    __shared__ float wsl[256];
    __shared__ float red[8];
    __shared__ float ctx[256];
    __shared__ float hid[128];
    __shared__ float wc1s[128 * 65];

    float v = scores[b * T_ + tid];
    float mx = v;
    #pragma unroll
    for (int off = 32; off > 0; off >>= 1) mx = fmaxf(mx, __shfl_xor(mx, off));
    if ((tid & 63) == 0) red[tid >> 6] = mx;
    __syncthreads();
    mx = fmaxf(fmaxf(red[0], red[1]), fmaxf(red[2], red[3]));
    float e = expf(v - mx);
    float s = e;
    #pragma unroll
    for (int off = 32; off > 0; off >>= 1) s += __shfl_xor(s, off);
    if ((tid & 63) == 0) red[4 + (tid >> 6)] = s;
    __syncthreads();
    float denom = red[4] + red[5] + red[6] + red[7];
    wsl[tid] = e / denom;
    __syncthreads();

    // ctx[f] = sum_t l1[b,t,f] * w[t]
    float acc = 0.f;
    const float* lb = l1 + (size_t)b * T_ * 256 + tid;
    #pragma unroll 4
    for (int t = 0; t < T_; ++t) acc += lb[(size_t)t * 256] * wsl[t];
    ctx[tid] = acc;
    __syncthreads();

    // hid = relu(ctx @ Wc1^T + bc1), Wc1 staged in LDS in 4 k-chunks
    float hacc = (tid < 128) ? bc1[tid] : 0.f;
    for (int kb = 0; kb < 4; ++kb) {
        for (int i = tid; i < 128 * 64; i += 256) {
            int jj = i >> 6, kk = i & 63;
            wc1s[jj * 65 + kk] = Wc1[jj * 256 + kb * 64 + kk];
        }
        __syncthreads();
        if (tid < 128) {
            #pragma unroll
            for (int kk = 0; kk < 64; ++kk)
                hacc += ctx[kb * 64 + kk] * wc1s[tid * 65 + kk];
        }
        __syncthreads();
    }
    if (tid < 128) hid[tid] = fmaxf(hacc, 0.f);
    __syncthreads();

    if (tid < NC_) {
        float a = bc2[tid];
        #pragma unroll
        for (int k = 0; k < 128; ++k) a += hid[k] * Wc2[tid * 128 + k];
        out[b * NC_ + tid] = a;
    }
}

// ---------------------------------------------------------------------------
extern "C" void kernel_launch(void* const* d_in, const int* in_sizes, int n_in,
                              void* d_out, int out_size, void* d_ws, size_t ws_size,
                              hipStream_t stream)
{
    const float* x    = (const float*)d_in[0];
    const float* adj  = (const float*)d_in[1];
    const float* Wg1  = (const float*)d_in[2];
    const float* bg1  = (const float*)d_in[3];
    const float* Wg2  = (const float*)d_in[4];
    const float* bg2  = (const float*)d_in[5];
    const float* Wih0 = (const float*)d_in[6];
    const float* Whh0 = (const float*)d_in[7];
    const float* bih0 = (const float*)d_in[8];
    const float* bhh0 = (const float*)d_in[9];
    const float* Wih1 = (const float*)d_in[10];
    const float* Whh1 = (const float*)d_in[11];
    const float* bih1 = (const float*)d_in[12];
    const float* bhh1 = (const float*)d_in[13];
    const float* Wa1  = (const float*)d_in[14];
    const float* ba1  = (const float*)d_in[15];
    const float* Wa2  = (const float*)d_in[16];
    const float* ba2  = (const float*)d_in[17];
    const float* Wc1  = (const float*)d_in[18];
    const float* bc1  = (const float*)d_in[19];
    const float* Wc2  = (const float*)d_in[20];
    const float* bc2  = (const float*)d_in[21];
    float* ws = (float*)d_ws;

    // workspace layout (floats); peak use ~148 MB
    float* seqc   = ws;                 // 4096*3904 = 15,990,784
    float* pre    = ws + 15990784;      // 2*16384*512 = 16,777,216 (pre0, then pre1)
    float* l0out  = ws + 32768000;      // 16384*256 = 4,194,304
    float* l1out  = ws;                 // reuse seq region (dead after GEMM0)
    float* scores = ws + 4194304;       // 16384 (still inside old seq region)

    for (int ch = 0; ch < 4; ++ch) {
        int m_base = ch * CHUNK_M;
        gcn_kernel<<<CHUNK_M, 256, 0, stream>>>(x, adj, Wg1, bg1, Wg2, bg2, seqc, m_base);
        gemm_bias_kernel<<<dim3(CHUNK_M / 128, 8), 256, 0, stream>>>(
            seqc, Wih0, bih0, bhh0, pre, NG_, m_base, M_TOT);
    }
    lstm_kernel<<<128, 1024, 0, stream>>>(pre, Whh0, l0out);
    gemm_bias_kernel<<<dim3(M_TOT / 128, 8), 256, 0, stream>>>(
        l0out, Wih1, bih1, bhh1, pre, 256, 0, M_TOT);
    lstm_kernel<<<128, 1024, 0, stream>>>(pre, Whh1, l1out);
    attn_scores_kernel<<<B_, 256, 0, stream>>>(l1out, Wa1, ba1, Wa2, ba2, scores);
    attn_head_kernel<<<B_, 256, 0, stream>>>(l1out, scores, Wc1, bc1, Wc2, bc2, (float*)d_out);
}

// Round 6
// 2035.680 us; speedup vs baseline: 1.8646x; 1.8646x over previous
//
#include <hip/hip_runtime.h>
#include <math.h>

#define B_    64
#define T_    256
#define N_    61
#define FIN_  3
#define GH_   64
#define LH_   128
#define NC_   10
#define NG_   3904      /* N_*GH_ */
#define M_TOT 16384     /* B_*T_  */
#define CHUNK_M 8192

typedef __attribute__((ext_vector_type(8))) short bf16x8;
typedef __attribute__((ext_vector_type(4))) float f32x4;

__device__ __forceinline__ float gelu_exact(float x) {
    return 0.5f * x * (1.0f + erff(x * 0.70710678118654752f));
}
__device__ __forceinline__ float sigmoidf_(float x) {
    return 1.0f / (1.0f + expf(-x));
}
__device__ __forceinline__ unsigned short f2bf(float f) {
    unsigned int u = __float_as_uint(f);
    u = (u + 0x7FFFu + ((u >> 16) & 1u)) >> 16;
    return (unsigned short)u;
}
__device__ __forceinline__ void store_h(float* p, float v) { *p = v; }
__device__ __forceinline__ void store_h(unsigned short* p, float v) { *p = f2bf(v); }

__device__ __forceinline__ void gload_lds16(const void* g, void* l) {
    __builtin_amdgcn_global_load_lds(
        (const __attribute__((address_space(1))) unsigned int*)g,
        (__attribute__((address_space(3))) unsigned int*)l,
        16, 0, 0);
}

// ---------------------------------------------------------------------------
// fp32 -> bf16 weight conversion (4 elems/thread). n4 = ELEMENT count / 4.
// ---------------------------------------------------------------------------
__global__ __launch_bounds__(256) void cvt_bf16_kernel(
    const float* __restrict__ in, unsigned short* __restrict__ out, int n4)
{
    int i = blockIdx.x * 256 + threadIdx.x;
    if (i < n4) {
        float4 v = reinterpret_cast<const float4*>(in)[i];
        ushort4 o;
        o.x = f2bf(v.x); o.y = f2bf(v.y); o.z = f2bf(v.z); o.w = f2bf(v.w);
        reinterpret_cast<ushort4*>(out)[i] = o;
    }
}

// ---------------------------------------------------------------------------
// GCN: one block per (b,t). Everything staged in LDS. Writes bf16 seq row.
// ---------------------------------------------------------------------------
__global__ __launch_bounds__(256) void gcn_kernel(
    const float* __restrict__ x, const float* __restrict__ adj,
    const float* __restrict__ W1, const float* __restrict__ b1,
    const float* __restrict__ W2, const float* __restrict__ b2,
    unsigned short* __restrict__ seqc, int m_base)
{
    __shared__ float adjs[N_ * N_];
    __shared__ float xs [N_ * FIN_ + 1];
    __shared__ float axs[N_ * FIN_ + 1];
    __shared__ float h1s [N_ * GH_];
    __shared__ float ah1s[N_ * GH_];
    __shared__ float w2s[GH_ * (GH_ + 1)];
    __shared__ float w1s[GH_ * FIN_];
    __shared__ float b1s[GH_], b2s[GH_];

    const int tid = threadIdx.x;
    const int m   = m_base + blockIdx.x;

    for (int i = tid; i < N_ * N_;   i += 256) adjs[i] = adj[i];
    for (int i = tid; i < N_ * FIN_; i += 256) xs[i]   = x[(size_t)m * (N_ * FIN_) + i];
    for (int i = tid; i < GH_ * FIN_; i += 256) w1s[i] = W1[i];
    if (tid < GH_) { b1s[tid] = b1[tid]; b2s[tid] = b2[tid]; }
    for (int i = tid; i < GH_ * GH_; i += 256) {
        int c = i >> 6, f = i & 63;
        w2s[c * 65 + f] = W2[i];
    }
    __syncthreads();

    if (tid < N_ * FIN_) {
        int n = tid / 3, f = tid - n * 3;
        float acc = 0.f;
        for (int mm = 0; mm < N_; ++mm) acc += adjs[n * N_ + mm] * xs[mm * 3 + f];
        axs[tid] = acc;
    }
    __syncthreads();

    for (int u = 0; u < 16; ++u) {
        int idx = tid + u * 256;
        if (idx < N_ * GH_) {
            int n = idx >> 6, c = idx & 63;
            float acc = b1s[c];
            acc += axs[n * 3 + 0] * w1s[c * 3 + 0];
            acc += axs[n * 3 + 1] * w1s[c * 3 + 1];
            acc += axs[n * 3 + 2] * w1s[c * 3 + 2];
            h1s[idx] = gelu_exact(acc);
        }
    }
    __syncthreads();

    for (int u = 0; u < 16; ++u) {
        int idx = tid + u * 256;
        if (idx < N_ * GH_) {
            int n = idx >> 6, c = idx & 63;
            float acc = 0.f;
            for (int mm = 0; mm < N_; ++mm) acc += adjs[n * N_ + mm] * h1s[mm * GH_ + c];
            ah1s[idx] = acc;
        }
    }
    __syncthreads();

    for (int u = 0; u < 16; ++u) {
        int idx = tid + u * 256;
        if (idx < N_ * GH_) {
            int n = idx >> 6, c = idx & 63;
            float acc = b2s[c];
            #pragma unroll
            for (int f = 0; f < GH_; ++f) acc += ah1s[n * GH_ + f] * w2s[c * 65 + f];
            seqc[(size_t)blockIdx.x * NG_ + idx] = f2bf(gelu_exact(acc));
        }
    }
}

// ---------------------------------------------------------------------------
// bf16 MFMA GEMM: C = A(Mc x K) @ W(1024 x K)^T + bias_a + bias_b
// 128x128 tile, 4 waves (2x2), 16x16x32 MFMA, BK=32, global_load_lds staging.
// Output scattered fp32 to [d][Mtot][512].
// ---------------------------------------------------------------------------
__global__ __launch_bounds__(256) void gemm_mfma_kernel(
    const unsigned short* __restrict__ A, const unsigned short* __restrict__ W,
    const float* __restrict__ bias_a, const float* __restrict__ bias_b,
    float* __restrict__ Cout, int K, int m_base, int Mtot)
{
    __shared__ unsigned short As[128 * 32];   // 8 KB, row-major [row][k], 64B/row
    __shared__ unsigned short Bs[128 * 32];   // 8 KB

    const int tid = threadIdx.x;
    const int w   = tid >> 6;            // wave 0..3
    const int l   = tid & 63;
    const int wr  = w >> 1, wc = w & 1;  // 2x2 wave grid, each wave 64x64
    const int lr  = l & 15, lk = l >> 4;

    const int m0 = blockIdx.x * 128;
    const int n0 = blockIdx.y * 128;

    f32x4 acc[4][4];
    #pragma unroll
    for (int i = 0; i < 4; ++i)
        #pragma unroll
        for (int j = 0; j < 4; ++j) acc[i][j] = (f32x4){0.f, 0.f, 0.f, 0.f};

    // staging: thread tid covers LDS bytes [tid*16, tid*16+16) == row tid>>2,
    // cols (tid&3)*8..+7  (linear [row][k] layout, 64 B/row)
    const int row_a0 = tid >> 2;
    const int cb     = (tid & 3) * 8;
    const unsigned short* aptr0 = A + (size_t)(m0 + row_a0) * K + cb;
    const unsigned short* aptr1 = A + (size_t)(m0 + row_a0 + 64) * K + cb;
    const unsigned short* bptr0 = W + (size_t)(n0 + row_a0) * K + cb;
    const unsigned short* bptr1 = W + (size_t)(n0 + row_a0 + 64) * K + cb;
    unsigned short* lA0 = &As[w * 512];               // wave-uniform LDS bases
    unsigned short* lA1 = &As[2048 + w * 512];
    unsigned short* lB0 = &Bs[w * 512];
    unsigned short* lB1 = &Bs[2048 + w * 512];

    for (int k0 = 0; k0 < K; k0 += 32) {
        gload_lds16(aptr0 + k0, lA0);
        gload_lds16(aptr1 + k0, lA1);
        gload_lds16(bptr0 + k0, lB0);
        gload_lds16(bptr1 + k0, lB1);
        __syncthreads();

        bf16x8 af[4], bfr[4];
        #pragma unroll
        for (int i = 0; i < 4; ++i)
            af[i] = *reinterpret_cast<const bf16x8*>(&As[(wr * 64 + i * 16 + lr) * 32 + lk * 8]);
        #pragma unroll
        for (int j = 0; j < 4; ++j)
            bfr[j] = *reinterpret_cast<const bf16x8*>(&Bs[(wc * 64 + j * 16 + lr) * 32 + lk * 8]);
        #pragma unroll
        for (int i = 0; i < 4; ++i)
            #pragma unroll
            for (int j = 0; j < 4; ++j)
                acc[i][j] = __builtin_amdgcn_mfma_f32_16x16x32_bf16(af[i], bfr[j], acc[i][j], 0, 0, 0);
        __syncthreads();
    }

    // epilogue: D lane map col=l&15 (n), row=(l>>4)*4+r (m)
    #pragma unroll
    for (int i = 0; i < 4; ++i) {
        #pragma unroll
        for (int j = 0; j < 4; ++j) {
            int n = n0 + wc * 64 + j * 16 + lr;
            float ba = bias_a[n] + bias_b[n];
            int d = n >> 9, g = n & 511;
            #pragma unroll
            for (int r = 0; r < 4; ++r) {
                int m = m_base + m0 + wr * 64 + i * 16 + lk * 4 + r;
                Cout[((size_t)d * Mtot + m) * 512 + g] = acc[i][j][r] + ba;
            }
        }
    }
}

// ---------------------------------------------------------------------------
// BiLSTM recurrence: one block per (dir,batch). 1024 threads.
// ---------------------------------------------------------------------------
template <typename OT>
__global__ __launch_bounds__(1024) void lstm_kernel(
    const float* __restrict__ pre,   // [d][b][t][512]
    const float* __restrict__ Whh,   // [2][512][128]
    OT* __restrict__ hout)           // [b][t][256]
{
    const int d   = blockIdx.x >> 6;
    const int b   = blockIdx.x & 63;
    const int tid = threadIdx.x;
    const int g   = tid & 511;
    const int kh  = tid >> 9;

    float w[64];
    const float* wsrc = Whh + ((size_t)d * 512 + g) * 128 + kh * 64;
    #pragma unroll
    for (int k = 0; k < 64; ++k) w[k] = wsrc[k];

    __shared__ __align__(16) float h_lds[128];
    __shared__ float part[1024];
    __shared__ float gates[512];

    if (tid < 128) h_lds[tid] = 0.f;
    float c = 0.f;
    __syncthreads();

    const float* prebase = pre + ((size_t)(d * B_ + b)) * T_ * 512;

    for (int s = 0; s < T_; ++s) {
        int t = d ? (T_ - 1 - s) : s;
        float p = (tid < 512) ? prebase[(size_t)t * 512 + g] : 0.f;

        float acc0 = 0.f, acc1 = 0.f;
        #pragma unroll
        for (int k4 = 0; k4 < 16; ++k4) {
            float4 hv = *reinterpret_cast<const float4*>(&h_lds[kh * 64 + k4 * 4]);
            acc0 += w[k4 * 4 + 0] * hv.x; acc1 += w[k4 * 4 + 1] * hv.y;
            acc0 += w[k4 * 4 + 2] * hv.z; acc1 += w[k4 * 4 + 3] * hv.w;
        }
        part[tid] = acc0 + acc1;
        __syncthreads();
        if (tid < 512) gates[g] = p + part[g] + part[g + 512];
        __syncthreads();
        if (tid < 128) {
            float gi = gates[tid], gf = gates[tid + 128];
            float gc = gates[tid + 256], go = gates[tid + 384];
            c = sigmoidf_(gf) * c + sigmoidf_(gi) * tanhf(gc);
            float h = sigmoidf_(go) * tanhf(c);
            h_lds[tid] = h;
            store_h(&hout[((size_t)b * T_ + t) * 256 + d * 128 + tid], h);
        }
        __syncthreads();
    }
}

// ---------------------------------------------------------------------------
// attention scores: block per b.
// ---------------------------------------------------------------------------
__global__ __launch_bounds__(256) void attn_scores_kernel(
    const float* __restrict__ l1, const float* __restrict__ Wa1,
    const float* __restrict__ ba1, const float* __restrict__ Wa2,
    const float* __restrict__ ba2, float* __restrict__ scores)
{
    const int b   = blockIdx.x;
    const int tid = threadIdx.x;
    const int j   = tid & 63, kq = tid >> 6;

    float w[64];
    const float* wsrc = Wa1 + j * 256 + kq * 64;
    #pragma unroll
    for (int k = 0; k < 64; ++k) w[k] = wsrc[k];

    __shared__ __align__(16) float row[256];
    __shared__ float part[256];
    const float* lb  = l1 + (size_t)b * T_ * 256;
    float wa2 = (tid < 64) ? Wa2[tid] : 0.f;
    float bj  = (tid < 64) ? ba1[tid] : 0.f;
    float bb2 = ba2[0];

    for (int t = 0; t < T_; ++t) {
        __syncthreads();
        row[tid] = lb[(size_t)t * 256 + tid];
        __syncthreads();
        float acc = 0.f;
        #pragma unroll
        for (int k4 = 0; k4 < 16; ++k4) {
            float4 hv = *reinterpret_cast<const float4*>(&row[kq * 64 + k4 * 4]);
            acc += w[k4 * 4 + 0] * hv.x + w[k4 * 4 + 1] * hv.y
                 + w[k4 * 4 + 2] * hv.z + w[k4 * 4 + 3] * hv.w;
        }
        part[tid] = acc;
        __syncthreads();
        if (tid < 64) {
            float dj = part[tid] + part[tid + 64] + part[tid + 128] + part[tid + 192];
            float sv = tanhf(dj + bj) * wa2;
            #pragma unroll
            for (int off = 32; off > 0; off >>= 1) sv += __shfl_xor(sv, off);
            if (tid == 0) scores[b * T_ + t] = sv + bb2;
        }
    }
}

// ---------------------------------------------------------------------------
// softmax + context + classifier head: block per b.
// ---------------------------------------------------------------------------
__global__ __launch_bounds__(256) void attn_head_kernel(
    const float* __restrict__ l1, const float* __restrict__ scores,
    const float* __restrict__ Wc1, const float* __restrict__ bc1,
    const float* __restrict__ Wc2, const float* __restrict__ bc2,
    float* __restrict__ out)
{
    const int b   = blockIdx.x;
    const int tid = threadIdx.x;
    __shared__ float wsl[256];
    __shared__ float red[8];
    __shared__ float ctx[256];
    __shared__ float hid[128];
    __shared__ float wc1s[128 * 65];

    float v = scores[b * T_ + tid];
    float mx = v;
    #pragma unroll
    for (int off = 32; off > 0; off >>= 1) mx = fmaxf(mx, __shfl_xor(mx, off));
    if ((tid & 63) == 0) red[tid >> 6] = mx;
    __syncthreads();
    mx = fmaxf(fmaxf(red[0], red[1]), fmaxf(red[2], red[3]));
    float e = expf(v - mx);
    float s = e;
    #pragma unroll
    for (int off = 32; off > 0; off >>= 1) s += __shfl_xor(s, off);
    if ((tid & 63) == 0) red[4 + (tid >> 6)] = s;
    __syncthreads();
    float denom = red[4] + red[5] + red[6] + red[7];
    wsl[tid] = e / denom;
    __syncthreads();

    float acc = 0.f;
    const float* lb = l1 + (size_t)b * T_ * 256 + tid;
    #pragma unroll 4
    for (int t = 0; t < T_; ++t) acc += lb[(size_t)t * 256] * wsl[t];
    ctx[tid] = acc;
    __syncthreads();

    float hacc = (tid < 128) ? bc1[tid] : 0.f;
    for (int kb = 0; kb < 4; ++kb) {
        for (int i = tid; i < 128 * 64; i += 256) {
            int jj = i >> 6, kk = i & 63;
            wc1s[jj * 65 + kk] = Wc1[jj * 256 + kb * 64 + kk];
        }
        __syncthreads();
        if (tid < 128) {
            #pragma unroll
            for (int kk = 0; kk < 64; ++kk)
                hacc += ctx[kb * 64 + kk] * wc1s[tid * 65 + kk];
        }
        __syncthreads();
    }
    if (tid < 128) hid[tid] = fmaxf(hacc, 0.f);
    __syncthreads();

    if (tid < NC_) {
        float a = bc2[tid];
        #pragma unroll
        for (int k = 0; k < 128; ++k) a += hid[k] * Wc2[tid * 128 + k];
        out[b * NC_ + tid] = a;
    }
}

// ---------------------------------------------------------------------------
extern "C" void kernel_launch(void* const* d_in, const int* in_sizes, int n_in,
                              void* d_out, int out_size, void* d_ws, size_t ws_size,
                              hipStream_t stream)
{
    const float* x    = (const float*)d_in[0];
    const float* adj  = (const float*)d_in[1];
    const float* Wg1  = (const float*)d_in[2];
    const float* bg1  = (const float*)d_in[3];
    const float* Wg2  = (const float*)d_in[4];
    const float* bg2  = (const float*)d_in[5];
    const float* Wih0 = (const float*)d_in[6];
    const float* Whh0 = (const float*)d_in[7];
    const float* bih0 = (const float*)d_in[8];
    const float* bhh0 = (const float*)d_in[9];
    const float* Wih1 = (const float*)d_in[10];
    const float* Whh1 = (const float*)d_in[11];
    const float* bih1 = (const float*)d_in[12];
    const float* bhh1 = (const float*)d_in[13];
    const float* Wa1  = (const float*)d_in[14];
    const float* ba1  = (const float*)d_in[15];
    const float* Wa2  = (const float*)d_in[16];
    const float* ba2  = (const float*)d_in[17];
    const float* Wc1  = (const float*)d_in[18];
    const float* bc1  = (const float*)d_in[19];
    const float* Wc2  = (const float*)d_in[20];
    const float* bc2  = (const float*)d_in[21];

    char* ws = (char*)d_ws;
    // Workspace layout (byte offsets, peak 142,737,408 B < 147.8 MB proven bound).
    // Phase 1 (GCN + GEMM0 chunks): seqb [0, 63,963,136)
    // Phase 2+: l0b [0, 8,388,608)  l1f [8,388,608, 25,165,824)  scr [25,165,824, +64K)
    //           (all reuse the dead seqb region, in dependency order)
    unsigned short* seqb = (unsigned short*)(ws);
    unsigned short* l0b  = (unsigned short*)(ws);
    float*          l1f  = (float*)(ws + 8388608);
    float*          scr  = (float*)(ws + 25165824);
    float*          pre  = (float*)(ws + 67108864);              // 67,108,864 B
    unsigned short* W0b  = (unsigned short*)(ws + 134217728);    // 7,995,392 B
    unsigned short* W1b  = (unsigned short*)(ws + 142213120);    // 524,288 B

    // weight conversions (bf16) — counts are ELEMENT counts from in_sizes
    const int n0e = in_sizes[6];    // 2*512*3904 = 3,997,696
    const int n1e = in_sizes[10];   // 2*512*256  = 262,144
    cvt_bf16_kernel<<<(n0e / 4 + 255) / 256, 256, 0, stream>>>(Wih0, W0b, n0e / 4);
    cvt_bf16_kernel<<<(n1e / 4 + 255) / 256, 256, 0, stream>>>(Wih1, W1b, n1e / 4);

    for (int ch = 0; ch < 2; ++ch) {
        int m_base = ch * CHUNK_M;
        gcn_kernel<<<CHUNK_M, 256, 0, stream>>>(x, adj, Wg1, bg1, Wg2, bg2, seqb, m_base);
        gemm_mfma_kernel<<<dim3(CHUNK_M / 128, 8), 256, 0, stream>>>(
            seqb, W0b, bih0, bhh0, pre, NG_, m_base, M_TOT);
    }
    lstm_kernel<<<128, 1024, 0, stream>>>(pre, Whh0, l0b);
    gemm_mfma_kernel<<<dim3(M_TOT / 128, 8), 256, 0, stream>>>(
        l0b, W1b, bih1, bhh1, pre, 256, 0, M_TOT);
    lstm_kernel<<<128, 1024, 0, stream>>>(pre, Whh1, l1f);
    attn_scores_kernel<<<B_, 256, 0, stream>>>(l1f, Wa1, ba1, Wa2, ba2, scr);
    attn_head_kernel<<<B_, 256, 0, stream>>>(l1f, scr, Wc1, bc1, Wc2, bc2, (float*)d_out);
}